// Round 4
// baseline (383.211 us; speedup 1.0000x reference)
//
#include <hip/hip_runtime.h>
#include <cstdint>
#include <cstddef>

// Problem constants
#define BATCH 4
#define SEQ   2048
#define CMOD  1024
#define NH    16
#define DH    64
#define LOG100 4.6051701859880914f
#define LOG2E  1.4426950408889634f

typedef __attribute__((ext_vector_type(8))) short bf16x8;
typedef __attribute__((ext_vector_type(4))) float f32x4;
typedef __attribute__((ext_vector_type(16))) float f32x16;

__device__ __forceinline__ float bf2f(uint16_t u) {
    union { uint32_t i; float f; } x; x.i = ((uint32_t)u) << 16; return x.f;
}
__device__ __forceinline__ uint16_t f2bf(float f) {
    union { float f; uint32_t i; } x; x.f = f;
    uint32_t u = x.i;
    return (uint16_t)((u + 0x7FFFu + ((u >> 16) & 1u)) >> 16);  // RNE
}
__device__ __forceinline__ float exp2_fast(float x) {
    float r; asm("v_exp_f32 %0, %1" : "=v"(r) : "v"(x)); return r;
}
__device__ __forceinline__ uint32_t cvt_pk_bf16(float lo, float hi) {
    uint32_t r;
    asm("v_cvt_pk_bf16_f32 %0, %1, %2" : "=v"(r) : "v"(lo), "v"(hi));
    return r;
}
__device__ __forceinline__ void p32swap(uint32_t& x, uint32_t& y) {
#if __has_builtin(__builtin_amdgcn_permlane32_swap)
    auto r = __builtin_amdgcn_permlane32_swap(x, y, false, false);
    x = r[0]; y = r[1];
#else
    asm volatile("v_permlane32_swap_b32 %0, %1\n\ts_nop 1" : "+v"(x), "+v"(y));
#endif
}

__device__ __forceinline__ void gload_lds16(const void* g, void* l) {
    __builtin_amdgcn_global_load_lds(
        (const __attribute__((address_space(1))) uint32_t*)g,
        (__attribute__((address_space(3))) uint32_t*)l,
        16, 0, 0);
}

// ---------------- fp32 -> bf16 convert ----------------
__global__ __launch_bounds__(256) void cvt_kernel(const float* __restrict__ in,
                                                  uint16_t* __restrict__ out, int n) {
    int i = (blockIdx.x * 256 + threadIdx.x) * 4;
    if (i >= n) return;
    float4 f = *(const float4*)(in + i);
    ushort4 o;
    o.x = f2bf(f.x); o.y = f2bf(f.y); o.z = f2bf(f.z); o.w = f2bf(f.w);
    *(ushort4*)(out + i) = o;
}

// ---------------- bf16 GEMM, B-transposed input (m97 structure) ----------------
// C[M,N] = A[M,K] * B[N,K]^T ; 128x128 tile, BK=32, 4 waves, 4x4 16x16x32 frags/wave
// mode 0: QKV epilogue -> q normalized*scale_h*log2e (bf16 [B,H,L,D]),
//         k normalized (bf16 [B,H,L,D]), v+bias pre-transposed (bf16 [B,H,D,L])
// mode 1: proj epilogue -> fp32 out + b_proj
__global__ __launch_bounds__(256) void gemm_bt_kernel(
    const uint16_t* __restrict__ A, const uint16_t* __restrict__ B,
    int M, int N, int K, int mode,
    uint16_t* __restrict__ qb, uint16_t* __restrict__ kb, uint16_t* __restrict__ vtb,
    const float* __restrict__ q_bias, const float* __restrict__ v_bias,
    const float* __restrict__ scale_mul_log,
    float* __restrict__ outp, const float* __restrict__ b_proj)
{
    __shared__ __align__(16) uint16_t As[128 * 32];
    __shared__ __align__(16) uint16_t Bs[128 * 32];
    const int t = threadIdx.x;
    const int wave = t >> 6, lane = t & 63;
    const int g = lane >> 4, c16 = lane & 15;
    const int m0 = blockIdx.x * 128, n0 = blockIdx.y * 128;
    const int wm = (wave >> 1) * 64, wn = (wave & 1) * 64;

    f32x4 acc[4][4];
#pragma unroll
    for (int mt = 0; mt < 4; mt++)
#pragma unroll
        for (int nt = 0; nt < 4; nt++) acc[mt][nt] = (f32x4){0.f, 0.f, 0.f, 0.f};

    for (int k0 = 0; k0 < K; k0 += 32) {
        __syncthreads();
#pragma unroll
        for (int i = 0; i < 2; i++) {
            int cc = i * 256 + t;           // 512 chunks of 8 elems
            int row = cc >> 2, col = (cc & 3) * 8;
            gload_lds16(A + (size_t)(m0 + row) * K + k0 + col, &As[cc * 8]);
            gload_lds16(B + (size_t)(n0 + row) * K + k0 + col, &Bs[cc * 8]);
        }
        __syncthreads();
        bf16x8 af[4], bfv[4];
#pragma unroll
        for (int mt = 0; mt < 4; mt++)
            af[mt] = *(const bf16x8*)&As[(wm + mt * 16 + c16) * 32 + g * 8];
#pragma unroll
        for (int nt = 0; nt < 4; nt++)
            bfv[nt] = *(const bf16x8*)&Bs[(wn + nt * 16 + c16) * 32 + g * 8];
#pragma unroll
        for (int mt = 0; mt < 4; mt++)
#pragma unroll
            for (int nt = 0; nt < 4; nt++)
                acc[mt][nt] = __builtin_amdgcn_mfma_f32_16x16x32_bf16(af[mt], bfv[nt], acc[mt][nt], 0, 0, 0);
    }

    if (mode == 0) {
        const int colbase = n0 + wn;          // multiple of 64 -> single (tt, head) per wave
        const int tt = colbase >> 10;
        const int cc0 = colbase & 1023;
        const int hh = cc0 >> 6;
        float qmul = 1.0f;
        if (tt == 0) qmul = __expf(fminf(scale_mul_log[hh], LOG100)) * LOG2E;
#pragma unroll
        for (int mt = 0; mt < 4; mt++) {
            float vals[4][4];
            float n2[4] = {0.f, 0.f, 0.f, 0.f};
#pragma unroll
            for (int nt = 0; nt < 4; nt++) {
                const int ci = cc0 + nt * 16 + c16;   // 0..1023 within qkv third
                float badd = 0.f;
                if (tt == 0) badd = q_bias[ci];
                else if (tt == 2) badd = v_bias[ci];
#pragma unroll
                for (int r = 0; r < 4; r++) {
                    float v = acc[mt][nt][r] + badd;
                    vals[nt][r] = v;
                    n2[r] += v * v;
                }
            }
            float rs[4];
            if (tt < 2) {   // L2-normalize q (with scale*log2e) and k over the 64-wide head dim
#pragma unroll
                for (int r = 0; r < 4; r++) {
                    float s = n2[r];
                    s += __shfl_xor(s, 1, 64);
                    s += __shfl_xor(s, 2, 64);
                    s += __shfl_xor(s, 4, 64);
                    s += __shfl_xor(s, 8, 64);
                    rs[r] = qmul / fmaxf(sqrtf(s), 1e-12f);
                }
            } else {
#pragma unroll
                for (int r = 0; r < 4; r++) rs[r] = 1.0f;
            }
#pragma unroll
            for (int nt = 0; nt < 4; nt++) {
                const int dd = (cc0 + nt * 16 + c16) & 63;
#pragma unroll
                for (int r = 0; r < 4; r++) {
                    const int row = m0 + wm + mt * 16 + g * 4 + r;   // b*2048 + l
                    const int bb = row >> 11, ll = row & 2047;
                    const size_t bhx = (size_t)bb * NH + hh;
                    const uint16_t val = f2bf(vals[nt][r] * rs[r]);
                    if (tt == 0)      qb[(bhx * SEQ + ll) * DH + dd] = val;
                    else if (tt == 1) kb[(bhx * SEQ + ll) * DH + dd] = val;
                    else              vtb[(bhx * DH + dd) * SEQ + ll] = val;  // transposed
                }
            }
        }
    } else {
#pragma unroll
        for (int mt = 0; mt < 4; mt++)
#pragma unroll
            for (int nt = 0; nt < 4; nt++)
#pragma unroll
                for (int r = 0; r < 4; r++) {
                    int row = m0 + wm + mt * 16 + g * 4 + r;
                    int col = n0 + wn + nt * 16 + c16;
                    outp[(size_t)row * N + col] = acc[mt][nt][r] + b_proj[col];
                }
    }
}

// ---------------- fused cosine-sim flash attention (batch-in-block, 32x32 MFMA) ----------------
// grid: 1024 blocks, gid = h*64 + qt ; block: 4 waves, wave w = batch w, 32 Q-rows
// Swapped QK^T with 32x32x16: S^T = mfma(K,Q) -> lane owns q-row (lane&31),
//   k = (r&3)+8*(r>>2)+4*hi  (m74/m101-verified C/D layout).
// Softmax: static max (logits bounded: scale<=4, |bias|<~0.12), p = exp2(S + bias*log2e).
// P repack: m214-v22 verified recipe — cvt_pk pairs + permlane32_swap only (no permlane16).
__global__ __launch_bounds__(256) void attn_kernel(
    const uint16_t* __restrict__ qb, const uint16_t* __restrict__ kb,
    const uint16_t* __restrict__ vtb, const float* __restrict__ bias,
    uint16_t* __restrict__ ob)
{
    __shared__ __align__(16) uint16_t Ks[4][64 * 64];   // per-batch [krow][d], rows XOR-swizzled
    __shared__ __align__(16) uint16_t Vs[4][64 * 64];   // per-batch [d][kcol], rows XOR-swizzled

    const int t = threadIdx.x;
    const int w = t >> 6, lane = t & 63;       // wave index == batch index
    const int c32 = lane & 31, hi = lane >> 5;

    const int h = blockIdx.x >> 6;
    const int qt = blockIdx.x & 63;
    const int q0 = qt * 32;
    const size_t bh = (size_t)w * NH + h;

    // Q fragments: 4 d-subtiles of 16; octet per hi (q pre-scaled by scale_h*log2e/||q||)
    bf16x8 qf[4];
    const uint16_t* qp = qb + (bh * SEQ + q0 + c32) * DH;
#pragma unroll
    for (int s = 0; s < 4; s++)
        qf[s] = *(const bf16x8*)(qp + s * 16 + hi * 8);

    f32x16 accO[2];
#pragma unroll
    for (int db = 0; db < 2; db++)
#pragma unroll
        for (int i = 0; i < 16; i++) accO[db][i] = 0.f;
    float lrun = 0.f;

    const float* bias_base = bias + ((size_t)h * SEQ + q0 + c32) * SEQ;

    for (int k0 = 0; k0 < SEQ; k0 += 64) {
        __syncthreads();   // previous tile's LDS reads complete
        // stage K and V^T for all 4 batches (16 chunks/thread), source pre-swizzled
#pragma unroll
        for (int i = 0; i < 8; i++) {
            int c = i * 256 + t;               // 0..2047
            int bw = c >> 9, cc = c & 511;
            int row = cc >> 3, jc = cc & 7, sj = jc ^ (row & 7);
            gload_lds16(kb + (((size_t)bw * NH + h) * SEQ + k0 + row) * DH + sj * 8, &Ks[bw][cc * 8]);
            gload_lds16(vtb + (((size_t)bw * NH + h) * DH + row) * SEQ + k0 + sj * 8, &Vs[bw][cc * 8]);
        }
        // bias float4 loads for own q-row (c32); k = k0 + kb2*32 + tt*8 + hi*4 + {0..3}
        // (all 4 waves read identical addresses -> L1 broadcast)
        float bbf[2][16];
#pragma unroll
        for (int kb2 = 0; kb2 < 2; kb2++)
#pragma unroll
            for (int tt = 0; tt < 4; tt++) {
                float4 v4 = *(const float4*)(bias_base + k0 + kb2 * 32 + tt * 8 + hi * 4);
                bbf[kb2][tt * 4 + 0] = v4.x;
                bbf[kb2][tt * 4 + 1] = v4.y;
                bbf[kb2][tt * 4 + 2] = v4.z;
                bbf[kb2][tt * 4 + 3] = v4.w;
            }
        __syncthreads();   // staging drained

        // S^T = K Q^T per 32-row k-block: reg r -> k_local = (r&3)+8*(r>>2)+4*hi
        f32x16 S[2];
#pragma unroll
        for (int kb2 = 0; kb2 < 2; kb2++)
#pragma unroll
            for (int i = 0; i < 16; i++) S[kb2][i] = 0.f;
#pragma unroll
        for (int s = 0; s < 4; s++) {
#pragma unroll
            for (int kb2 = 0; kb2 < 2; kb2++) {
                int rr = kb2 * 32 + c32;
                bf16x8 kf = *(const bf16x8*)((const uint8_t*)Ks[w] + rr * 128 +
                                             (((2 * s + hi) * 16) ^ ((rr & 7) << 4)));
                S[kb2] = __builtin_amdgcn_mfma_f32_32x32x16_bf16(kf, qf[s], S[kb2], 0, 0, 0);
            }
        }

        // softmax (static max) + m214 repack -> PV A-fragments
        bf16x8 pa[4];
#pragma unroll
        for (int kb2 = 0; kb2 < 2; kb2++) {
            float p[16];
            float lp = 0.f;
#pragma unroll
            for (int r = 0; r < 16; r++) {
                p[r] = exp2_fast(fmaf(bbf[kb2][r], LOG2E, S[kb2][r]));
                lp += p[r];
            }
            lrun += lp;
#pragma unroll
            for (int cp = 0; cp < 2; cp++) {
                uint32_t X0 = cvt_pk_bf16(p[8 * cp + 0], p[8 * cp + 1]);
                uint32_t X1 = cvt_pk_bf16(p[8 * cp + 2], p[8 * cp + 3]);
                uint32_t Y0 = cvt_pk_bf16(p[8 * cp + 4], p[8 * cp + 5]);
                uint32_t Y1 = cvt_pk_bf16(p[8 * cp + 6], p[8 * cp + 7]);
                p32swap(X0, Y0);   // X0 -> word0 (k=8hi+{0,1}), Y0 -> word2 (k=8hi+4+{0,1})
                p32swap(X1, Y1);   // X1 -> word1,                Y1 -> word3
                union { uint32_t u[4]; bf16x8 v; } pu;
                pu.u[0] = X0; pu.u[1] = X1; pu.u[2] = Y0; pu.u[3] = Y1;
                pa[kb2 * 2 + cp] = pu.v;
            }
        }

        // O += P V : 2 d-blocks x 4 k-subtiles of 16
#pragma unroll
        for (int c = 0; c < 4; c++) {
#pragma unroll
            for (int db = 0; db < 2; db++) {
                int rr = db * 32 + c32;
                bf16x8 vf = *(const bf16x8*)((const uint8_t*)Vs[w] + rr * 128 +
                                             (((2 * c + hi) * 16) ^ ((rr & 7) << 4)));
                accO[db] = __builtin_amdgcn_mfma_f32_32x32x16_bf16(pa[c], vf, accO[db], 0, 0, 0);
            }
        }
    }

    // finalize: one shuffle pair for row sums, redistribute, O /= l, write bf16
    float ssum = lrun + __shfl_xor(lrun, 32, 64);
    float inv = 1.0f / ssum;                    // valid for q-row = c32 on all lanes
    float linv[16];
#pragma unroll
    for (int r = 0; r < 16; r++)
        linv[r] = __shfl(inv, (r & 3) + 8 * (r >> 2) + 4 * hi, 64);
#pragma unroll
    for (int db = 0; db < 2; db++)
#pragma unroll
        for (int r = 0; r < 16; r++) {
            int rowq = (r & 3) + 8 * (r >> 2) + 4 * hi;
            ob[((size_t)w * SEQ + q0 + rowq) * CMOD + h * DH + db * 32 + c32] =
                f2bf(accO[db][r] * linv[r]);
        }
}

// ---------------- launch ----------------
extern "C" void kernel_launch(void* const* d_in, const int* in_sizes, int n_in,
                              void* d_out, int out_size, void* d_ws, size_t ws_size,
                              hipStream_t stream) {
    const float* x             = (const float*)d_in[0];
    const float* attn_bias     = (const float*)d_in[1];
    const float* W_qkv         = (const float*)d_in[2];
    const float* q_bias        = (const float*)d_in[3];
    const float* v_bias        = (const float*)d_in[4];
    const float* scale_mul_log = (const float*)d_in[5];
    const float* W_proj        = (const float*)d_in[6];
    const float* b_proj        = (const float*)d_in[7];
    float* out = (float*)d_out;

    uint8_t* ws = (uint8_t*)d_ws;
    size_t off = 0;
    auto alloc = [&](size_t bytes) { uint8_t* p = ws + off; off += (bytes + 255) & ~(size_t)255; return p; };
    uint16_t* xb     = (uint16_t*)alloc((size_t)8192 * 1024 * 2);
    uint16_t* wqkvb  = (uint16_t*)alloc((size_t)3072 * 1024 * 2);
    uint16_t* wprojb = (uint16_t*)alloc((size_t)1024 * 1024 * 2);
    uint16_t* qb     = (uint16_t*)alloc((size_t)BATCH * NH * SEQ * DH * 2);
    uint16_t* kb     = (uint16_t*)alloc((size_t)BATCH * NH * SEQ * DH * 2);
    uint16_t* vtb    = (uint16_t*)alloc((size_t)BATCH * NH * SEQ * DH * 2);
    uint16_t* ob     = (uint16_t*)alloc((size_t)BATCH * SEQ * CMOD * 2);
    (void)ws_size;

    cvt_kernel<<<8192, 256, 0, stream>>>(x, xb, 8388608);
    cvt_kernel<<<3072, 256, 0, stream>>>(W_qkv, wqkvb, 3145728);
    cvt_kernel<<<1024, 256, 0, stream>>>(W_proj, wprojb, 1048576);

    dim3 g1(64, 24);
    gemm_bt_kernel<<<g1, 256, 0, stream>>>(xb, wqkvb, 8192, 3072, 1024, 0,
                                           qb, kb, vtb, q_bias, v_bias, scale_mul_log,
                                           nullptr, nullptr);

    attn_kernel<<<1024, 256, 0, stream>>>(qb, kb, vtb, attn_bias, ob);

    dim3 g3(64, 8);
    gemm_bt_kernel<<<g3, 256, 0, stream>>>(ob, wprojb, 8192, 1024, 1024, 1,
                                           nullptr, nullptr, nullptr, nullptr, nullptr, nullptr,
                                           out, b_proj);
}